// Round 3
// baseline (442.625 us; speedup 1.0000x reference)
//
#include <hip/hip_runtime.h>
#include <hip/hip_bf16.h>
#include <stdint.h>

// DecoderSelfAttention: B=8, S=2048, D=1024 (d_k=d_v=d_model)
// Pipeline (all bf16 MFMA, fp32 accumulate):
//   prep: x->bf16, W->W^T bf16 ; [Q|K] = x@[Wq|Wk] ; V^T = Wv^T @ x^T ;
//   P' = exp(QK^T/32) (unnormalized, causal tiles only) + row-sum partials ;
//   rl = 1/rowsum ; out = (P' @ V) * rl.
// MFMA operands are SWAPPED (mfma(bfr, af)) so the C-layout's reg axis is the
// B-operand: each lane holds 4 consecutive N-cols at one M-row -> all epilogues
// use packed 8B/16B stores and row-reductions need only 2 shuffles.

typedef __bf16 bf16_t;
typedef __bf16 bf16x4 __attribute__((ext_vector_type(4)));
typedef __bf16 bf16x8 __attribute__((ext_vector_type(8)));
typedef float  floatx4 __attribute__((ext_vector_type(4)));

#define NB 8
#define SS 2048
#define DD 1024
#define INV_SCALE 0.03125f   // 1/sqrt(1024)

__device__ __forceinline__ void async_ld16(const void* g, void* l) {
  __builtin_amdgcn_global_load_lds(
      (const __attribute__((address_space(1))) void*)g,
      (__attribute__((address_space(3))) void*)l, 16, 0, 0);
}

// 128x128 tile GEMM core, C = A * B^T, A[M,K] row-major, B[N,K] row-major,
// both bf16, BK=32, 256 threads (4 waves in 2x2), acc 4x4 of 16x16x32 MFMA.
// SWAPPED operand order: acc[i][j] = mfma(bfr[j], af[i], acc[i][j]).
// C mapping per lane: M-row = wm*64 + i*16 + (lane&15),
//                     N-col = wn*64 + j*16 + (lane>>4)*4 + reg.
__device__ __forceinline__ void mm_core(const bf16_t* __restrict__ Ab,
                                        const bf16_t* __restrict__ Bb,
                                        int lda, int ldb, int kTiles,
                                        bf16_t* sA, bf16_t* sB,
                                        floatx4 acc[4][4]) {
  const int t    = threadIdx.x;
  const int lane = t & 63;
  const int wm   = (t >> 6) >> 1;
  const int wn   = (t >> 6) & 1;
  const int sr   = t >> 2;          // staging row 0..63
  const int sc   = (t & 3) * 8;     // staging col 0,8,16,24
  const int fm   = lane & 15;
  const int fk   = (lane >> 4) * 8;

  const bf16_t* ga0 = Ab + (size_t)sr * lda + sc;
  const bf16_t* ga1 = Ab + (size_t)(sr + 64) * lda + sc;
  const bf16_t* gb0 = Bb + (size_t)sr * ldb + sc;
  const bf16_t* gb1 = Bb + (size_t)(sr + 64) * ldb + sc;
  bf16_t* la0 = sA + t * 8;
  bf16_t* la1 = sA + (t + 256) * 8;
  bf16_t* lb0 = sB + t * 8;
  bf16_t* lb1 = sB + (t + 256) * 8;

  const bf16_t* pa = sA + (wm * 64 + fm) * 32 + fk;
  const bf16_t* pb = sB + (wn * 64 + fm) * 32 + fk;

  for (int kt = 0; kt < kTiles; ++kt) {
    const int ko = kt * 32;
    async_ld16(ga0 + ko, la0);
    async_ld16(ga1 + ko, la1);
    async_ld16(gb0 + ko, lb0);
    async_ld16(gb1 + ko, lb1);
    __syncthreads();   // drains vmcnt(0): LDS tiles complete
    bf16x8 af[4], bfr[4];
#pragma unroll
    for (int i = 0; i < 4; ++i) af[i]  = *(const bf16x8*)(pa + i * 512);
#pragma unroll
    for (int j = 0; j < 4; ++j) bfr[j] = *(const bf16x8*)(pb + j * 512);
#pragma unroll
    for (int i = 0; i < 4; ++i)
#pragma unroll
      for (int j = 0; j < 4; ++j)
        acc[i][j] = __builtin_amdgcn_mfma_f32_16x16x32_bf16(bfr[j], af[i], acc[i][j], 0, 0, 0);
    __syncthreads();   // all reads done before next staging overwrites
  }
}

__device__ __forceinline__ void zero_acc(floatx4 acc[4][4]) {
#pragma unroll
  for (int i = 0; i < 4; ++i)
#pragma unroll
    for (int j = 0; j < 4; ++j)
      acc[i][j] = floatx4{0.f, 0.f, 0.f, 0.f};
}

// ---------------- fused converters: x->bf16 and W->W^T bf16 ----------------

__global__ __launch_bounds__(256) void prep(const float* __restrict__ x,
                                            const float* __restrict__ Wq,
                                            const float* __restrict__ Wk,
                                            const float* __restrict__ Wv,
                                            bf16_t* __restrict__ xb,
                                            bf16_t* __restrict__ Wt) {
  __shared__ float tile[32][33];
  const int bid = blockIdx.x;
  const int t = threadIdx.x;
  if (bid < 16384) {
    size_t i = (size_t)bid * 256 + t;
    float4 v = ((const float4*)x)[i];
    bf16x4 o = {(bf16_t)v.x, (bf16_t)v.y, (bf16_t)v.z, (bf16_t)v.w};
    ((bf16x4*)xb)[i] = o;
  } else {
    const int wb = bid - 16384;
    const int z = wb >> 10;                 // 0,1,2 -> Wq,Wk,Wv
    const int rem = wb & 1023;
    const float* W = (z == 0) ? Wq : (z == 1 ? Wk : Wv);
    bf16_t* O = Wt + (size_t)z * DD * DD;
    const int ty = t >> 3;
    const int tx = t & 7;
    const int k0 = (rem >> 5) * 32, n0 = (rem & 31) * 32;
    float4 v = *(const float4*)(W + (size_t)(k0 + ty) * DD + n0 + tx * 4);
    tile[ty][tx * 4 + 0] = v.x;
    tile[ty][tx * 4 + 1] = v.y;
    tile[ty][tx * 4 + 2] = v.z;
    tile[ty][tx * 4 + 3] = v.w;
    __syncthreads();
    bf16x4 o = {(bf16_t)tile[tx * 4 + 0][ty], (bf16_t)tile[tx * 4 + 1][ty],
                (bf16_t)tile[tx * 4 + 2][ty], (bf16_t)tile[tx * 4 + 3][ty]};
    *(bf16x4*)(O + (size_t)(n0 + ty) * DD + k0 + tx * 4) = o;
  }
}

// ---------------- generic GEMM, bf16 C, packed 8B stores ----------------

__global__ __launch_bounds__(256) void gemm_bf16(
    const bf16_t* __restrict__ A, const bf16_t* __restrict__ B,
    bf16_t* __restrict__ C, int lda, int ldb, int ldc, int kTiles,
    unsigned long long aStride, unsigned long long bStride, unsigned long long cStride) {
  __shared__ __attribute__((aligned(16))) bf16_t sA[128 * 32];
  __shared__ __attribute__((aligned(16))) bf16_t sB[128 * 32];
  const int mt = blockIdx.x, nt = blockIdx.y, bz = blockIdx.z;
  const bf16_t* Ab = A + (size_t)bz * aStride + (size_t)mt * 128 * lda;
  const bf16_t* Bb = B + (size_t)bz * bStride + (size_t)nt * 128 * ldb;
  bf16_t* Cb = C + (size_t)bz * cStride + (size_t)mt * 128 * ldc + nt * 128;
  floatx4 acc[4][4];
  zero_acc(acc);
  mm_core(Ab, Bb, lda, ldb, kTiles, sA, sB, acc);
  const int lane = threadIdx.x & 63;
  const int wm = (threadIdx.x >> 6) >> 1, wn = (threadIdx.x >> 6) & 1;
  const int m0 = wm * 64 + (lane & 15);
  const int n0 = wn * 64 + (lane >> 4) * 4;
#pragma unroll
  for (int i = 0; i < 4; ++i)
#pragma unroll
    for (int j = 0; j < 4; ++j) {
      floatx4 a = acc[i][j];
      bf16x4 o = {(bf16_t)a[0], (bf16_t)a[1], (bf16_t)a[2], (bf16_t)a[3]};
      *(bf16x4*)(Cb + (size_t)(m0 + i * 16) * ldc + n0 + j * 16) = o;
    }
}

// ---------------- QK^T -> P' = exp(s) bf16 (causal tiles only) + row-sum partials ----------------

__global__ __launch_bounds__(256) void qk_p(
    const bf16_t* __restrict__ Q, const bf16_t* __restrict__ K,
    bf16_t* __restrict__ P, float* __restrict__ lpart) {
  // triangular decode: blockIdx.x in [0,136) -> (qi, ki), ki <= qi
  const int tt = blockIdx.x;
  int qi = (int)((sqrtf(8.0f * tt + 1.0f) - 1.0f) * 0.5f);
  while ((qi + 1) * (qi + 2) / 2 <= tt) ++qi;
  while (qi * (qi + 1) / 2 > tt) --qi;
  const int ki = tt - qi * (qi + 1) / 2;
  const int b = blockIdx.z;

  __shared__ __attribute__((aligned(16))) bf16_t sA[128 * 32];
  __shared__ __attribute__((aligned(16))) bf16_t sB[128 * 32];
  __shared__ float reds[2][128];
  const bf16_t* Ab = Q + ((size_t)b * SS + qi * 128) * (size_t)(2 * DD);
  const bf16_t* Bb = K + ((size_t)b * SS + ki * 128) * (size_t)(2 * DD);
  floatx4 acc[4][4];
  zero_acc(acc);
  mm_core(Ab, Bb, 2 * DD, 2 * DD, DD / 32, sA, sB, acc);

  const int lane = threadIdx.x & 63;
  const int wm = (threadIdx.x >> 6) >> 1, wn = (threadIdx.x >> 6) & 1;
  const bool diag = (ki == qi);
  bf16_t* Pb = P + (size_t)b * SS * SS;
  const int qloc0 = wm * 64 + (lane & 15);        // + i*16
  const int kvb0  = wn * 64 + (lane >> 4) * 4;    // + j*16, + reg

#pragma unroll
  for (int i = 0; i < 4; ++i) {
    const int qrow = qloc0 + i * 16;
    float partial = 0.f;
#pragma unroll
    for (int j = 0; j < 4; ++j) {
      const int kvb = kvb0 + j * 16;
      floatx4 p;
#pragma unroll
      for (int r = 0; r < 4; ++r) {
        const float s = acc[i][j][r] * INV_SCALE;
        p[r] = (diag && (kvb + r) > qrow) ? 0.f : __expf(s);
        partial += p[r];
      }
      bf16x4 o = {(bf16_t)p[0], (bf16_t)p[1], (bf16_t)p[2], (bf16_t)p[3]};
      *(bf16x4*)(Pb + (size_t)(qi * 128 + qrow) * SS + ki * 128 + kvb) = o;
    }
    partial += __shfl_xor(partial, 16);
    partial += __shfl_xor(partial, 32);
    if ((lane >> 4) == 0) reds[wn][qrow] = partial;
  }
  __syncthreads();
  const int t = threadIdx.x;
  if (t < 128) {
    size_t row = (size_t)b * SS + qi * 128 + t;
    lpart[row * 16 + ki] = reds[0][t] + reds[1][t];
  }
}

__global__ __launch_bounds__(256) void lsum(
    const float* __restrict__ lpart, float* __restrict__ rl) {
  const int idx = blockIdx.x * 256 + threadIdx.x;   // 0..B*S-1
  const int q = idx & (SS - 1);
  const int nch = (q >> 7) + 1;
  const float* lp = lpart + (size_t)idx * 16;
  float L = 0.f;
  for (int c = 0; c < nch; ++c) L += lp[c];
  rl[idx] = 1.0f / L;
}

// ---------------- PV GEMM (causal-truncated K-loop), *rl epilogue, fp32 out ----------------
// blockIdx.x decode pairs qi with 15-qi per 256-block round so that, under a
// sequential block->CU round-robin, each CU's 4 blocks sum to constant work.

__global__ __launch_bounds__(256) void pv_gemm(
    const bf16_t* __restrict__ P, const bf16_t* __restrict__ Vt,
    const float* __restrict__ rl, float* __restrict__ Out) {
  const int i  = blockIdx.x;        // 0..1023
  const int c  = i & 255;
  const int k  = i >> 8;            // round 0..3
  const int q0 = c & 15;
  const int h  = c >> 4;
  const int qi = (k & 1) ? (15 - q0) : q0;
  const int nj = h & 7;
  const int b  = (h >> 3) | (k << 1);

  __shared__ __attribute__((aligned(16))) bf16_t sA[128 * 32];
  __shared__ __attribute__((aligned(16))) bf16_t sB[128 * 32];
  const bf16_t* Ab = P + (size_t)b * SS * SS + (size_t)qi * 128 * SS;
  const bf16_t* Bb = Vt + (size_t)b * DD * SS + (size_t)nj * 128 * SS;
  float* Cb = Out + (size_t)b * SS * DD + (size_t)qi * 128 * DD + nj * 128;
  floatx4 acc[4][4];
  zero_acc(acc);
  mm_core(Ab, Bb, SS, SS, (qi + 1) * 4, sA, sB, acc);   // K = (qi+1)*128
  const int lane = threadIdx.x & 63;
  const int wm = (threadIdx.x >> 6) >> 1, wn = (threadIdx.x >> 6) & 1;
  const int m0 = wm * 64 + (lane & 15);          // q row
  const int n0 = wn * 64 + (lane >> 4) * 4;      // dv col
  const float* rlb = rl + (size_t)b * SS + qi * 128;
#pragma unroll
  for (int i2 = 0; i2 < 4; ++i2) {
    const float scale = rlb[m0 + i2 * 16];
    float* crow = Cb + (size_t)(m0 + i2 * 16) * DD + n0;
#pragma unroll
    for (int j = 0; j < 4; ++j) {
      floatx4 o = acc[i2][j];
      o[0] *= scale; o[1] *= scale; o[2] *= scale; o[3] *= scale;
      *(floatx4*)(crow + j * 16) = o;
    }
  }
}

// ---------------- launch ----------------

extern "C" void kernel_launch(void* const* d_in, const int* in_sizes, int n_in,
                              void* d_out, int out_size, void* d_ws, size_t ws_size,
                              hipStream_t stream) {
  const float* x  = (const float*)d_in[0];
  const float* Wq = (const float*)d_in[1];
  const float* Wk = (const float*)d_in[2];
  const float* Wv = (const float*)d_in[3];
  float* out = (float*)d_out;

  char* ws = (char*)d_ws;
  // workspace layout (bytes)
  bf16_t* xb   = (bf16_t*)(ws);                      // 33,554,432  x bf16 [B*S, D]
  bf16_t* Wt   = (bf16_t*)(ws + 33554432ull);        //  6,291,456  Wq^T,Wk^T,Wv^T bf16 [N,K] each
  bf16_t* QKb  = (bf16_t*)(ws + 39845888ull);        // 67,108,864  [Q|K] bf16 [B*S, 2048]
  bf16_t* VtB  = (bf16_t*)(ws + 106954752ull);       // 33,554,432  V^T bf16 [B, D, S]
  bf16_t* Pb   = (bf16_t*)(ws + 140509184ull);       // 67,108,864  P' bf16 [B, S, S] (causal area only)
  float*  lpart= (float*)(ws + 207618048ull);        //  1,048,576  row-sum partials [B*S, 16]
  float*  rl   = (float*)(ws + 208666624ull);        //     65,536  1/rowsum [B*S]
  (void)in_sizes; (void)n_in; (void)out_size; (void)ws_size;

  // 1. convert x + convert/transpose weights (one dispatch)
  prep<<<16384 + 3072, 256, 0, stream>>>(x, Wq, Wk, Wv, xb, Wt);
  // 2. [Q|K] = x @ [Wq|Wk]  (M=16384, N=2048, K=1024)
  gemm_bf16<<<dim3(128, 16, 1), 256, 0, stream>>>(xb, Wt, QKb, DD, DD, 2 * DD, DD / 32, 0, 0, 0);
  // 3. V^T[b] = Wv^T @ x[b]^T : A=Wv^T [D,K], B=x[b] [S,K], C=Vt[b] [D,S]
  gemm_bf16<<<dim3(8, 16, NB), 256, 0, stream>>>(Wt + 2097152, xb, VtB, DD, DD, SS, DD / 32,
                                                 0ull, (unsigned long long)SS * DD,
                                                 (unsigned long long)DD * SS);
  // 4. P' = exp(QK^T/32) on causal tiles + row-sum partials
  qk_p<<<dim3(136, 1, NB), 256, 0, stream>>>(QKb, QKb + DD, Pb, lpart);
  // 5. rl = 1/rowsum
  lsum<<<64, 256, 0, stream>>>(lpart, rl);
  // 6. out = (P' @ V) * rl  via Vt, causal-truncated K, CU-balanced block decode
  pv_gemm<<<1024, 256, 0, stream>>>(Pb, VtB, rl, out);
}

// Round 4
// 404.966 us; speedup vs baseline: 1.0930x; 1.0930x over previous
//
#include <hip/hip_runtime.h>
#include <hip/hip_bf16.h>
#include <stdint.h>

// DecoderSelfAttention: B=8, S=2048, D=1024 (d_k=d_v=d_model)
// Pipeline (all bf16 MFMA, fp32 accumulate), 4 dispatches:
//   prep: x->bf16, W->W^T bf16
//   proj: [Q|K] = x@[Wq|Wk]  AND  V^T = Wv^T@x^T   (one fused dispatch)
//   qk_p: P' = exp(QK^T/32) on causal tiles + row-sum partials
//   pv:   out = (P' @ V) * (1/rowsum)   (rowsum folded into prologue)
// mm_core uses BK=64 (2 MFMA K-halves per barrier pair) with XOR-swizzled
// 16B-unit LDS placement (unit = row*8 + (cc ^ (row&7))) so global_load_lds'
// lane-linear destination constraint still yields even bank-group spread.
// MFMA operands SWAPPED (mfma(bfr, af)): lane C = 4 consecutive N-cols at one
// M-row -> packed 8B/16B epilogue stores, 2-shuffle row reductions.

typedef __bf16 bf16_t;
typedef __bf16 bf16x4 __attribute__((ext_vector_type(4)));
typedef __bf16 bf16x8 __attribute__((ext_vector_type(8)));
typedef float  floatx4 __attribute__((ext_vector_type(4)));

#define NB 8
#define SS 2048
#define DD 1024
#define INV_SCALE 0.03125f   // 1/sqrt(1024)

__device__ __forceinline__ void async_ld16(const void* g, void* l) {
  __builtin_amdgcn_global_load_lds(
      (const __attribute__((address_space(1))) void*)g,
      (__attribute__((address_space(3))) void*)l, 16, 0, 0);
}

// 128x128 tile GEMM core, C = A * B^T, A[M,K] row-major, B[N,K] row-major,
// both bf16, BK=64, 256 threads (4 waves 2x2), acc 4x4 of 16x16x32 MFMA.
// kTiles counts 64-wide K steps. sA/sB are 128*64 bf16 (16 KB each).
__device__ __forceinline__ void mm_core(const bf16_t* __restrict__ Ab,
                                        const bf16_t* __restrict__ Bb,
                                        int lda, int ldb, int kTiles,
                                        bf16_t* sA, bf16_t* sB,
                                        floatx4 acc[4][4]) {
  const int t    = threadIdx.x;
  const int lane = t & 63;
  const int wm   = (t >> 6) >> 1;
  const int wn   = (t >> 6) & 1;
  const int fm   = lane & 15;
  const int q    = lane >> 4;       // 0..3
  const int xo   = fm & 7;          // per-lane XOR swizzle key

  // staging: 4 instrs each side; unit u = k*256+t ; row=u>>3 ; cc=(u&7)^(row&7)
  const bf16_t* ga[4]; const bf16_t* gb[4];
  bf16_t* la[4]; bf16_t* lb[4];
#pragma unroll
  for (int k = 0; k < 4; ++k) {
    const int u   = k * 256 + t;
    const int row = u >> 3;
    const int cc  = (u & 7) ^ (row & 7);
    ga[k] = Ab + (size_t)row * lda + cc * 8;
    gb[k] = Bb + (size_t)row * ldb + cc * 8;
    la[k] = sA + u * 8;
    lb[k] = sB + u * 8;
  }

  // fragment bases: element (R, kcol) lives at unit R*8 + ((kcol/8)^(R&7))
  const bf16_t* pa = sA + (wm * 64 + fm) * 64;
  const bf16_t* pb = sB + (wn * 64 + fm) * 64;

  for (int kt = 0; kt < kTiles; ++kt) {
    const int ko = kt * 64;
#pragma unroll
    for (int k = 0; k < 4; ++k) async_ld16(ga[k] + ko, la[k]);
#pragma unroll
    for (int k = 0; k < 4; ++k) async_ld16(gb[k] + ko, lb[k]);
    __syncthreads();   // drains vmcnt(0): LDS tiles complete
#pragma unroll
    for (int h = 0; h < 2; ++h) {
      const int co = ((h * 4 + q) ^ xo) * 8;
      bf16x8 af[4], bfr[4];
#pragma unroll
      for (int i = 0; i < 4; ++i) af[i]  = *(const bf16x8*)(pa + i * 1024 + co);
#pragma unroll
      for (int j = 0; j < 4; ++j) bfr[j] = *(const bf16x8*)(pb + j * 1024 + co);
#pragma unroll
      for (int i = 0; i < 4; ++i)
#pragma unroll
        for (int j = 0; j < 4; ++j)
          acc[i][j] = __builtin_amdgcn_mfma_f32_16x16x32_bf16(bfr[j], af[i], acc[i][j], 0, 0, 0);
    }
    __syncthreads();   // all reads done before next staging overwrites
  }
}

__device__ __forceinline__ void zero_acc(floatx4 acc[4][4]) {
#pragma unroll
  for (int i = 0; i < 4; ++i)
#pragma unroll
    for (int j = 0; j < 4; ++j)
      acc[i][j] = floatx4{0.f, 0.f, 0.f, 0.f};
}

// ---------------- fused converters: x->bf16 and W->W^T bf16 ----------------

__global__ __launch_bounds__(256) void prep(const float* __restrict__ x,
                                            const float* __restrict__ Wq,
                                            const float* __restrict__ Wk,
                                            const float* __restrict__ Wv,
                                            bf16_t* __restrict__ xb,
                                            bf16_t* __restrict__ Wt) {
  __shared__ float tile[32][33];
  const int bid = blockIdx.x;
  const int t = threadIdx.x;
  if (bid < 16384) {
    size_t i = (size_t)bid * 256 + t;
    float4 v = ((const float4*)x)[i];
    bf16x4 o = {(bf16_t)v.x, (bf16_t)v.y, (bf16_t)v.z, (bf16_t)v.w};
    ((bf16x4*)xb)[i] = o;
  } else {
    const int wb = bid - 16384;
    const int z = wb >> 10;                 // 0,1,2 -> Wq,Wk,Wv
    const int rem = wb & 1023;
    const float* W = (z == 0) ? Wq : (z == 1 ? Wk : Wv);
    bf16_t* O = Wt + (size_t)z * DD * DD;
    const int ty = t >> 3;
    const int tx = t & 7;
    const int k0 = (rem >> 5) * 32, n0 = (rem & 31) * 32;
    float4 v = *(const float4*)(W + (size_t)(k0 + ty) * DD + n0 + tx * 4);
    tile[ty][tx * 4 + 0] = v.x;
    tile[ty][tx * 4 + 1] = v.y;
    tile[ty][tx * 4 + 2] = v.z;
    tile[ty][tx * 4 + 3] = v.w;
    __syncthreads();
    bf16x4 o = {(bf16_t)tile[tx * 4 + 0][ty], (bf16_t)tile[tx * 4 + 1][ty],
                (bf16_t)tile[tx * 4 + 2][ty], (bf16_t)tile[tx * 4 + 3][ty]};
    *(bf16x4*)(O + (size_t)(n0 + ty) * DD + k0 + tx * 4) = o;
  }
}

// ---------------- fused projection GEMMs: [Q|K] = x@[Wq|Wk] and V^T = Wv^T@x^T ----------------
// bid < 2048: QK-proj tile (mt 0..127, nt 0..15), A=xb, B=Wt(qk), C=QKb (ldc 2048)
// bid >= 2048: V^T tile: m 0..7 (dv), n 0..15 (seq), b 0..7; A=Wv^T, B=xb[b], C=VtB[b]

__global__ __launch_bounds__(256) void proj_gemm(
    const bf16_t* __restrict__ xb, const bf16_t* __restrict__ Wt,
    bf16_t* __restrict__ QKb, bf16_t* __restrict__ VtB) {
  __shared__ __attribute__((aligned(16))) bf16_t sA[128 * 64];
  __shared__ __attribute__((aligned(16))) bf16_t sB[128 * 64];
  const int bid = blockIdx.x;
  const bf16_t* Ab; const bf16_t* Bb; bf16_t* Cb;
  if (bid < 2048) {
    const int mt = bid >> 4, nt = bid & 15;
    Ab = xb + (size_t)mt * 128 * DD;
    Bb = Wt + (size_t)nt * 128 * DD;
    Cb = QKb + (size_t)mt * 128 * (2 * DD) + nt * 128;
  } else {
    const int idx = bid - 2048;
    const int m = idx & 7, n = (idx >> 3) & 15, b = idx >> 7;
    Ab = Wt + (size_t)2 * DD * DD + (size_t)m * 128 * DD;
    Bb = xb + (size_t)b * SS * DD + (size_t)n * 128 * DD;
    Cb = VtB + (size_t)b * DD * SS + (size_t)m * 128 * SS + n * 128;
  }
  floatx4 acc[4][4];
  zero_acc(acc);
  mm_core(Ab, Bb, DD, DD, DD / 64, sA, sB, acc);
  const int lane = threadIdx.x & 63;
  const int wm = (threadIdx.x >> 6) >> 1, wn = (threadIdx.x >> 6) & 1;
  const int m0 = wm * 64 + (lane & 15);
  const int n0 = wn * 64 + (lane >> 4) * 4;
  const int ldc = 2 * DD;   // both outputs have row stride 2048
#pragma unroll
  for (int i = 0; i < 4; ++i)
#pragma unroll
    for (int j = 0; j < 4; ++j) {
      floatx4 a = acc[i][j];
      bf16x4 o = {(bf16_t)a[0], (bf16_t)a[1], (bf16_t)a[2], (bf16_t)a[3]};
      *(bf16x4*)(Cb + (size_t)(m0 + i * 16) * ldc + n0 + j * 16) = o;
    }
}

// ---------------- QK^T -> P' = exp(s) bf16 (causal tiles only) + row-sum partials ----------------

__global__ __launch_bounds__(256) void qk_p(
    const bf16_t* __restrict__ Q, const bf16_t* __restrict__ K,
    bf16_t* __restrict__ P, float* __restrict__ lpart) {
  // triangular decode: blockIdx.x in [0,136) -> (qi, ki), ki <= qi
  const int tt = blockIdx.x;
  int qi = (int)((sqrtf(8.0f * tt + 1.0f) - 1.0f) * 0.5f);
  while ((qi + 1) * (qi + 2) / 2 <= tt) ++qi;
  while (qi * (qi + 1) / 2 > tt) --qi;
  const int ki = tt - qi * (qi + 1) / 2;
  const int b = blockIdx.z;

  __shared__ __attribute__((aligned(16))) bf16_t sA[128 * 64];
  __shared__ __attribute__((aligned(16))) bf16_t sB[128 * 64];
  __shared__ float reds[2][128];
  const bf16_t* Ab = Q + ((size_t)b * SS + qi * 128) * (size_t)(2 * DD);
  const bf16_t* Bb = K + ((size_t)b * SS + ki * 128) * (size_t)(2 * DD);
  floatx4 acc[4][4];
  zero_acc(acc);
  mm_core(Ab, Bb, 2 * DD, 2 * DD, DD / 64, sA, sB, acc);

  const int lane = threadIdx.x & 63;
  const int wm = (threadIdx.x >> 6) >> 1, wn = (threadIdx.x >> 6) & 1;
  const bool diag = (ki == qi);
  bf16_t* Pb = P + (size_t)b * SS * SS;
  const int qloc0 = wm * 64 + (lane & 15);        // + i*16
  const int kvb0  = wn * 64 + (lane >> 4) * 4;    // + j*16, + reg

#pragma unroll
  for (int i = 0; i < 4; ++i) {
    const int qrow = qloc0 + i * 16;
    float partial = 0.f;
#pragma unroll
    for (int j = 0; j < 4; ++j) {
      const int kvb = kvb0 + j * 16;
      floatx4 p;
#pragma unroll
      for (int r = 0; r < 4; ++r) {
        const float s = acc[i][j][r] * INV_SCALE;
        p[r] = (diag && (kvb + r) > qrow) ? 0.f : __expf(s);
        partial += p[r];
      }
      bf16x4 o = {(bf16_t)p[0], (bf16_t)p[1], (bf16_t)p[2], (bf16_t)p[3]};
      *(bf16x4*)(Pb + (size_t)(qi * 128 + qrow) * SS + ki * 128 + kvb) = o;
    }
    partial += __shfl_xor(partial, 16);
    partial += __shfl_xor(partial, 32);
    if ((lane >> 4) == 0) reds[wn][qrow] = partial;
  }
  __syncthreads();
  const int t = threadIdx.x;
  if (t < 128) {
    size_t row = (size_t)b * SS + qi * 128 + t;
    lpart[row * 16 + ki] = reds[0][t] + reds[1][t];
  }
}

// ---------------- PV GEMM (causal-truncated K-loop), rowsum+scale folded, fp32 out ----------------
// blockIdx.x decode pairs qi with 15-qi per 256-block round for CU load balance.

__global__ __launch_bounds__(256) void pv_gemm(
    const bf16_t* __restrict__ P, const bf16_t* __restrict__ Vt,
    const float* __restrict__ lpart, float* __restrict__ Out) {
  const int i  = blockIdx.x;        // 0..1023
  const int c  = i & 255;
  const int k  = i >> 8;            // round 0..3
  const int q0 = c & 15;
  const int h  = c >> 4;
  const int qi = (k & 1) ? (15 - q0) : q0;
  const int nj = h & 7;
  const int b  = (h >> 3) | (k << 1);

  __shared__ __attribute__((aligned(16))) bf16_t sA[128 * 64];
  __shared__ __attribute__((aligned(16))) bf16_t sB[128 * 64];
  __shared__ float sRl[128];
  // fold rowsum: rl = 1/sum(lpart[row][0..qi])
  const int t = threadIdx.x;
  if (t < 128) {
    const float* lp = lpart + ((size_t)b * SS + qi * 128 + t) * 16;
    float L = 0.f;
    for (int ci = 0; ci <= qi; ++ci) L += lp[ci];
    sRl[t] = 1.0f / L;
  }
  const bf16_t* Ab = P + (size_t)b * SS * SS + (size_t)qi * 128 * SS;
  const bf16_t* Bb = Vt + (size_t)b * DD * SS + (size_t)nj * 128 * SS;
  float* Cb = Out + (size_t)b * SS * DD + (size_t)qi * 128 * DD + nj * 128;
  floatx4 acc[4][4];
  zero_acc(acc);
  mm_core(Ab, Bb, SS, SS, (qi + 1) * 2, sA, sB, acc);   // K = (qi+1)*128
  const int lane = threadIdx.x & 63;
  const int wm = (threadIdx.x >> 6) >> 1, wn = (threadIdx.x >> 6) & 1;
  const int m0 = wm * 64 + (lane & 15);          // q row
  const int n0 = wn * 64 + (lane >> 4) * 4;      // dv col
#pragma unroll
  for (int i2 = 0; i2 < 4; ++i2) {
    const float scale = sRl[m0 + i2 * 16];
    float* crow = Cb + (size_t)(m0 + i2 * 16) * DD + n0;
#pragma unroll
    for (int j = 0; j < 4; ++j) {
      floatx4 o = acc[i2][j];
      o[0] *= scale; o[1] *= scale; o[2] *= scale; o[3] *= scale;
      *(floatx4*)(crow + j * 16) = o;
    }
  }
}

// ---------------- launch ----------------

extern "C" void kernel_launch(void* const* d_in, const int* in_sizes, int n_in,
                              void* d_out, int out_size, void* d_ws, size_t ws_size,
                              hipStream_t stream) {
  const float* x  = (const float*)d_in[0];
  const float* Wq = (const float*)d_in[1];
  const float* Wk = (const float*)d_in[2];
  const float* Wv = (const float*)d_in[3];
  float* out = (float*)d_out;

  char* ws = (char*)d_ws;
  // workspace layout (bytes)
  bf16_t* xb   = (bf16_t*)(ws);                      // 33,554,432  x bf16 [B*S, D]
  bf16_t* Wt   = (bf16_t*)(ws + 33554432ull);        //  6,291,456  Wq^T,Wk^T,Wv^T bf16 [N,K] each
  bf16_t* QKb  = (bf16_t*)(ws + 39845888ull);        // 67,108,864  [Q|K] bf16 [B*S, 2048]
  bf16_t* VtB  = (bf16_t*)(ws + 106954752ull);       // 33,554,432  V^T bf16 [B, D, S]
  bf16_t* Pb   = (bf16_t*)(ws + 140509184ull);       // 67,108,864  P' bf16 [B, S, S] (causal area only)
  float*  lpart= (float*)(ws + 207618048ull);        //  1,048,576  row-sum partials [B*S, 16]
  (void)in_sizes; (void)n_in; (void)out_size; (void)ws_size;

  // 1. convert x + convert/transpose weights (one dispatch)
  prep<<<16384 + 3072, 256, 0, stream>>>(x, Wq, Wk, Wv, xb, Wt);
  // 2. [Q|K] = x @ [Wq|Wk] (2048 tiles) fused with V^T = Wv^T @ x^T (1024 tiles)
  proj_gemm<<<3072, 256, 0, stream>>>(xb, Wt, QKb, VtB);
  // 3. P' = exp(QK^T/32) on causal tiles + row-sum partials
  qk_p<<<dim3(136, 1, NB), 256, 0, stream>>>(QKb, QKb + DD, Pb, lpart);
  // 4. out = (P' @ V) * (1/rowsum), causal-truncated K, CU-balanced block decode
  pv_gemm<<<1024, 256, 0, stream>>>(Pb, VtB, lpart, out);
}

// Round 5
// 369.297 us; speedup vs baseline: 1.1986x; 1.0966x over previous
//
#include <hip/hip_runtime.h>
#include <hip/hip_bf16.h>
#include <stdint.h>

// DecoderSelfAttention: B=8, S=2048, D=1024 (d_k=d_v=d_model)
// Pipeline (all bf16 MFMA, fp32 accumulate), 5 dispatches:
//   prep:    x->bf16, W->W^T bf16
//   qkproj:  [Q|K] = x@[Wq|Wk]      (grid mt-fastest: measured-best L2 reuse)
//   vproj:   V^T = Wv^T@x^T         (nb-fastest: XCD keeps its xb panels in L2)
//   qk_p:    P' = exp(QK^T/32) causal tiles + row-sum partials  (XCD==batch)
//   pv:      out = (P' @ V) * 1/rowsum                          (XCD==batch)
// FETCH_SIZE behaves as L2-fill traffic: block->XCD assignment (bid mod 8)
// determines which panels each XCD's 4MB L2 must stream. Orderings above keep
// per-XCD working sets < 4MB.
// mm_core: BK=64, XOR-swizzled 16B-unit LDS placement (conflict-free, meas. 0),
// swapped MFMA operands (lane C = 4 consecutive N-cols at one M-row).

typedef __bf16 bf16_t;
typedef __bf16 bf16x4 __attribute__((ext_vector_type(4)));
typedef __bf16 bf16x8 __attribute__((ext_vector_type(8)));
typedef float  floatx4 __attribute__((ext_vector_type(4)));

#define NB 8
#define SS 2048
#define DD 1024
#define INV_SCALE 0.03125f   // 1/sqrt(1024)

__device__ __forceinline__ void async_ld16(const void* g, void* l) {
  __builtin_amdgcn_global_load_lds(
      (const __attribute__((address_space(1))) void*)g,
      (__attribute__((address_space(3))) void*)l, 16, 0, 0);
}

// 128x128 tile GEMM core, C = A * B^T, A[M,K] row-major, B[N,K] row-major,
// both bf16, BK=64, 256 threads (4 waves 2x2), acc 4x4 of 16x16x32 MFMA.
// kTiles counts 64-wide K steps. sA/sB are 128*64 bf16 (16 KB each).
__device__ __forceinline__ void mm_core(const bf16_t* __restrict__ Ab,
                                        const bf16_t* __restrict__ Bb,
                                        int lda, int ldb, int kTiles,
                                        bf16_t* sA, bf16_t* sB,
                                        floatx4 acc[4][4]) {
  const int t    = threadIdx.x;
  const int lane = t & 63;
  const int wm   = (t >> 6) >> 1;
  const int wn   = (t >> 6) & 1;
  const int fm   = lane & 15;
  const int q    = lane >> 4;       // 0..3
  const int xo   = fm & 7;          // per-lane XOR swizzle key

  // staging: 4 instrs each side; unit u = k*256+t ; row=u>>3 ; cc=(u&7)^(row&7)
  const bf16_t* ga[4]; const bf16_t* gb[4];
  bf16_t* la[4]; bf16_t* lb[4];
#pragma unroll
  for (int k = 0; k < 4; ++k) {
    const int u   = k * 256 + t;
    const int row = u >> 3;
    const int cc  = (u & 7) ^ (row & 7);
    ga[k] = Ab + (size_t)row * lda + cc * 8;
    gb[k] = Bb + (size_t)row * ldb + cc * 8;
    la[k] = sA + u * 8;
    lb[k] = sB + u * 8;
  }

  // fragment bases: element (R, kcol) lives at unit R*8 + ((kcol/8)^(R&7))
  const bf16_t* pa = sA + (wm * 64 + fm) * 64;
  const bf16_t* pb = sB + (wn * 64 + fm) * 64;

  for (int kt = 0; kt < kTiles; ++kt) {
    const int ko = kt * 64;
#pragma unroll
    for (int k = 0; k < 4; ++k) async_ld16(ga[k] + ko, la[k]);
#pragma unroll
    for (int k = 0; k < 4; ++k) async_ld16(gb[k] + ko, lb[k]);
    __syncthreads();   // drains vmcnt(0): LDS tiles complete
#pragma unroll
    for (int h = 0; h < 2; ++h) {
      const int co = ((h * 4 + q) ^ xo) * 8;
      bf16x8 af[4], bfr[4];
#pragma unroll
      for (int i = 0; i < 4; ++i) af[i]  = *(const bf16x8*)(pa + i * 1024 + co);
#pragma unroll
      for (int j = 0; j < 4; ++j) bfr[j] = *(const bf16x8*)(pb + j * 1024 + co);
#pragma unroll
      for (int i = 0; i < 4; ++i)
#pragma unroll
        for (int j = 0; j < 4; ++j)
          acc[i][j] = __builtin_amdgcn_mfma_f32_16x16x32_bf16(bfr[j], af[i], acc[i][j], 0, 0, 0);
    }
    __syncthreads();   // all reads done before next staging overwrites
  }
}

__device__ __forceinline__ void zero_acc(floatx4 acc[4][4]) {
#pragma unroll
  for (int i = 0; i < 4; ++i)
#pragma unroll
    for (int j = 0; j < 4; ++j)
      acc[i][j] = floatx4{0.f, 0.f, 0.f, 0.f};
}

// ---------------- fused converters: x->bf16 and W->W^T bf16 ----------------

__global__ __launch_bounds__(256) void prep(const float* __restrict__ x,
                                            const float* __restrict__ Wq,
                                            const float* __restrict__ Wk,
                                            const float* __restrict__ Wv,
                                            bf16_t* __restrict__ xb,
                                            bf16_t* __restrict__ Wt) {
  __shared__ float tile[32][33];
  const int bid = blockIdx.x;
  const int t = threadIdx.x;
  if (bid < 16384) {
    size_t i = (size_t)bid * 256 + t;
    float4 v = ((const float4*)x)[i];
    bf16x4 o = {(bf16_t)v.x, (bf16_t)v.y, (bf16_t)v.z, (bf16_t)v.w};
    ((bf16x4*)xb)[i] = o;
  } else {
    const int wb = bid - 16384;
    const int z = wb >> 10;                 // 0,1,2 -> Wq,Wk,Wv
    const int rem = wb & 1023;
    const float* W = (z == 0) ? Wq : (z == 1 ? Wk : Wv);
    bf16_t* O = Wt + (size_t)z * DD * DD;
    const int ty = t >> 3;
    const int tx = t & 7;
    const int k0 = (rem >> 5) * 32, n0 = (rem & 31) * 32;
    float4 v = *(const float4*)(W + (size_t)(k0 + ty) * DD + n0 + tx * 4);
    tile[ty][tx * 4 + 0] = v.x;
    tile[ty][tx * 4 + 1] = v.y;
    tile[ty][tx * 4 + 2] = v.z;
    tile[ty][tx * 4 + 3] = v.w;
    __syncthreads();
    bf16x4 o = {(bf16_t)tile[tx * 4 + 0][ty], (bf16_t)tile[tx * 4 + 1][ty],
                (bf16_t)tile[tx * 4 + 2][ty], (bf16_t)tile[tx * 4 + 3][ty]};
    *(bf16x4*)(O + (size_t)(n0 + ty) * DD + k0 + tx * 4) = o;
  }
}

// ---------------- QK projection: [Q|K] = x @ [Wq|Wk] ----------------
// grid dim3(128,16): mt fastest (measured-best L2 behavior, r2: 70MB fetch)

__global__ __launch_bounds__(256) void qkproj_gemm(
    const bf16_t* __restrict__ xb, const bf16_t* __restrict__ Wt,
    bf16_t* __restrict__ QKb) {
  __shared__ __attribute__((aligned(16))) bf16_t sA[128 * 64];
  __shared__ __attribute__((aligned(16))) bf16_t sB[128 * 64];
  const int mt = blockIdx.x, nt = blockIdx.y;
  const bf16_t* Ab = xb + (size_t)mt * 128 * DD;
  const bf16_t* Bb = Wt + (size_t)nt * 128 * DD;
  bf16_t* Cb = QKb + (size_t)mt * 128 * (2 * DD) + nt * 128;
  floatx4 acc[4][4];
  zero_acc(acc);
  mm_core(Ab, Bb, DD, DD, DD / 64, sA, sB, acc);
  const int lane = threadIdx.x & 63;
  const int wm = (threadIdx.x >> 6) >> 1, wn = (threadIdx.x >> 6) & 1;
  const int m0 = wm * 64 + (lane & 15);
  const int n0 = wn * 64 + (lane >> 4) * 4;
#pragma unroll
  for (int i = 0; i < 4; ++i)
#pragma unroll
    for (int j = 0; j < 4; ++j) {
      floatx4 a = acc[i][j];
      bf16x4 o = {(bf16_t)a[0], (bf16_t)a[1], (bf16_t)a[2], (bf16_t)a[3]};
      *(bf16x4*)(Cb + (size_t)(m0 + i * 16) * (2 * DD) + n0 + j * 16) = o;
    }
}

// ---------------- V projection: V^T[b] = Wv^T @ x[b]^T ----------------
// 1D grid 1024: nb = bid&127 (fastest), m = bid>>7.
// XCD = bid mod 8 = nb mod 8: each XCD keeps its 16 xb panels (4MB) resident
// across the m-sweep; Wv panels re-fetched 8x (16MB total) -> fill ~48MB.

__global__ __launch_bounds__(256) void vproj_gemm(
    const bf16_t* __restrict__ xb, const bf16_t* __restrict__ Wt,
    bf16_t* __restrict__ VtB) {
  __shared__ __attribute__((aligned(16))) bf16_t sA[128 * 64];
  __shared__ __attribute__((aligned(16))) bf16_t sB[128 * 64];
  const int bid = blockIdx.x;
  const int nb = bid & 127;
  const int m  = bid >> 7;          // 0..7 (dv tile)
  const int n  = nb & 15;           // seq tile
  const int b  = nb >> 4;           // batch
  const bf16_t* Ab = Wt + (size_t)2 * DD * DD + (size_t)m * 128 * DD;
  const bf16_t* Bb = xb + (size_t)b * SS * DD + (size_t)n * 128 * DD;
  bf16_t* Cb = VtB + (size_t)b * DD * SS + (size_t)m * 128 * SS + n * 128;
  floatx4 acc[4][4];
  zero_acc(acc);
  mm_core(Ab, Bb, DD, DD, DD / 64, sA, sB, acc);
  const int lane = threadIdx.x & 63;
  const int wm = (threadIdx.x >> 6) >> 1, wn = (threadIdx.x >> 6) & 1;
  const int m0 = wm * 64 + (lane & 15);
  const int n0 = wn * 64 + (lane >> 4) * 4;
#pragma unroll
  for (int i = 0; i < 4; ++i)
#pragma unroll
    for (int j = 0; j < 4; ++j) {
      floatx4 a = acc[i][j];
      bf16x4 o = {(bf16_t)a[0], (bf16_t)a[1], (bf16_t)a[2], (bf16_t)a[3]};
      *(bf16x4*)(Cb + (size_t)(m0 + i * 16) * SS + n0 + j * 16) = o;
    }
}

// ---------------- QK^T -> P' = exp(s) bf16 (causal tiles only) + row-sum partials ----------------
// 1D grid 1088: b = bid&7 (XCD==batch), tt = 135-(bid>>3) (qi descending).

__global__ __launch_bounds__(256) void qk_p(
    const bf16_t* __restrict__ Q, const bf16_t* __restrict__ K,
    bf16_t* __restrict__ P, float* __restrict__ lpart) {
  const int b  = blockIdx.x & 7;
  const int tt = 135 - (blockIdx.x >> 3);
  int qi = (int)((sqrtf(8.0f * tt + 1.0f) - 1.0f) * 0.5f);
  while ((qi + 1) * (qi + 2) / 2 <= tt) ++qi;
  while (qi * (qi + 1) / 2 > tt) --qi;
  const int ki = tt - qi * (qi + 1) / 2;

  __shared__ __attribute__((aligned(16))) bf16_t sA[128 * 64];
  __shared__ __attribute__((aligned(16))) bf16_t sB[128 * 64];
  __shared__ float reds[2][128];
  const bf16_t* Ab = Q + ((size_t)b * SS + qi * 128) * (size_t)(2 * DD);
  const bf16_t* Bb = K + ((size_t)b * SS + ki * 128) * (size_t)(2 * DD);
  floatx4 acc[4][4];
  zero_acc(acc);
  mm_core(Ab, Bb, 2 * DD, 2 * DD, DD / 64, sA, sB, acc);

  const int lane = threadIdx.x & 63;
  const int wm = (threadIdx.x >> 6) >> 1, wn = (threadIdx.x >> 6) & 1;
  const bool diag = (ki == qi);
  bf16_t* Pb = P + (size_t)b * SS * SS;
  const int qloc0 = wm * 64 + (lane & 15);        // + i*16
  const int kvb0  = wn * 64 + (lane >> 4) * 4;    // + j*16, + reg

#pragma unroll
  for (int i = 0; i < 4; ++i) {
    const int qrow = qloc0 + i * 16;
    float partial = 0.f;
#pragma unroll
    for (int j = 0; j < 4; ++j) {
      const int kvb = kvb0 + j * 16;
      floatx4 p;
#pragma unroll
      for (int r = 0; r < 4; ++r) {
        const float s = acc[i][j][r] * INV_SCALE;
        p[r] = (diag && (kvb + r) > qrow) ? 0.f : __expf(s);
        partial += p[r];
      }
      bf16x4 o = {(bf16_t)p[0], (bf16_t)p[1], (bf16_t)p[2], (bf16_t)p[3]};
      *(bf16x4*)(Pb + (size_t)(qi * 128 + qrow) * SS + ki * 128 + kvb) = o;
    }
    partial += __shfl_xor(partial, 16);
    partial += __shfl_xor(partial, 32);
    if ((lane >> 4) == 0) reds[wn][qrow] = partial;
  }
  __syncthreads();
  const int t = threadIdx.x;
  if (t < 128) {
    size_t row = (size_t)b * SS + qi * 128 + t;
    lpart[row * 16 + ki] = reds[0][t] + reds[1][t];
  }
}

// ---------------- PV GEMM (causal-truncated K-loop), rowsum+scale folded, fp32 out ----------------
// 1D grid 1024: b = bid&7 (XCD==batch), nj = (bid>>3)&7 (innermost: 8 nj blocks
// for one P panel run consecutively on the same XCD), qi = 15-(bid>>6) desc.

__global__ __launch_bounds__(256) void pv_gemm(
    const bf16_t* __restrict__ P, const bf16_t* __restrict__ Vt,
    const float* __restrict__ lpart, float* __restrict__ Out) {
  const int bid = blockIdx.x;
  const int b  = bid & 7;
  const int nj = (bid >> 3) & 7;
  const int qi = 15 - (bid >> 6);

  __shared__ __attribute__((aligned(16))) bf16_t sA[128 * 64];
  __shared__ __attribute__((aligned(16))) bf16_t sB[128 * 64];
  __shared__ float sRl[128];
  // fold rowsum: rl = 1/sum(lpart[row][0..qi])
  const int t = threadIdx.x;
  if (t < 128) {
    const float* lp = lpart + ((size_t)b * SS + qi * 128 + t) * 16;
    float L = 0.f;
    for (int ci = 0; ci <= qi; ++ci) L += lp[ci];
    sRl[t] = 1.0f / L;
  }
  const bf16_t* Ab = P + (size_t)b * SS * SS + (size_t)qi * 128 * SS;
  const bf16_t* Bb = Vt + (size_t)b * DD * SS + (size_t)nj * 128 * SS;
  float* Cb = Out + (size_t)b * SS * DD + (size_t)qi * 128 * DD + nj * 128;
  floatx4 acc[4][4];
  zero_acc(acc);
  mm_core(Ab, Bb, SS, SS, (qi + 1) * 2, sA, sB, acc);   // K = (qi+1)*128
  const int lane = threadIdx.x & 63;
  const int wm = (threadIdx.x >> 6) >> 1, wn = (threadIdx.x >> 6) & 1;
  const int m0 = wm * 64 + (lane & 15);          // q row
  const int n0 = wn * 64 + (lane >> 4) * 4;      // dv col
#pragma unroll
  for (int i2 = 0; i2 < 4; ++i2) {
    const float scale = sRl[m0 + i2 * 16];
    float* crow = Cb + (size_t)(m0 + i2 * 16) * DD + n0;
#pragma unroll
    for (int j = 0; j < 4; ++j) {
      floatx4 o = acc[i2][j];
      o[0] *= scale; o[1] *= scale; o[2] *= scale; o[3] *= scale;
      *(floatx4*)(crow + j * 16) = o;
    }
  }
}

// ---------------- launch ----------------

extern "C" void kernel_launch(void* const* d_in, const int* in_sizes, int n_in,
                              void* d_out, int out_size, void* d_ws, size_t ws_size,
                              hipStream_t stream) {
  const float* x  = (const float*)d_in[0];
  const float* Wq = (const float*)d_in[1];
  const float* Wk = (const float*)d_in[2];
  const float* Wv = (const float*)d_in[3];
  float* out = (float*)d_out;

  char* ws = (char*)d_ws;
  // workspace layout (bytes)
  bf16_t* xb   = (bf16_t*)(ws);                      // 33,554,432  x bf16 [B*S, D]
  bf16_t* Wt   = (bf16_t*)(ws + 33554432ull);        //  6,291,456  Wq^T,Wk^T,Wv^T bf16 [N,K] each
  bf16_t* QKb  = (bf16_t*)(ws + 39845888ull);        // 67,108,864  [Q|K] bf16 [B*S, 2048]
  bf16_t* VtB  = (bf16_t*)(ws + 106954752ull);       // 33,554,432  V^T bf16 [B, D, S]
  bf16_t* Pb   = (bf16_t*)(ws + 140509184ull);       // 67,108,864  P' bf16 [B, S, S] (causal area only)
  float*  lpart= (float*)(ws + 207618048ull);        //  1,048,576  row-sum partials [B*S, 16]
  (void)in_sizes; (void)n_in; (void)out_size; (void)ws_size;

  // 1. convert x + convert/transpose weights (one dispatch)
  prep<<<16384 + 3072, 256, 0, stream>>>(x, Wq, Wk, Wv, xb, Wt);
  // 2. [Q|K] = x @ [Wq|Wk]  (M=16384, N=2048, K=1024), mt-fastest
  qkproj_gemm<<<dim3(128, 16), 256, 0, stream>>>(xb, Wt, QKb);
  // 3. V^T = Wv^T @ x^T, nb-fastest (XCD-resident xb panels)
  vproj_gemm<<<1024, 256, 0, stream>>>(xb, Wt, VtB);
  // 4. P' = exp(QK^T/32) on causal tiles + row-sum partials, XCD==batch
  qk_p<<<1088, 256, 0, stream>>>(QKb, QKb + DD, Pb, lpart);
  // 5. out = (P' @ V) * (1/rowsum), causal K-truncation, XCD==batch, nj inner
  pv_gemm<<<1024, 256, 0, stream>>>(Pb, VtB, lpart, out);
}